// Round 16
// baseline (241.974 us; speedup 1.0000x reference)
//
#include <hip/hip_runtime.h>
#include <hip/hip_bf16.h>

#define H_DIM 1024
#define E_NUM 8
#define F_DIM 2048
#define N_TOK 2048   // B*S
typedef unsigned int uint;
typedef short bf16x8 __attribute__((ext_vector_type(8)));
typedef float f32x4 __attribute__((ext_vector_type(4)));

// ws layout
#define WS_CNT   0
#define WS_OFF   64
#define WS_LIST  256                       // int[8*2048]
#define WS_W     (WS_LIST + 8*N_TOK*4)     // float[4096]
#define WS_G     131072                    // bf16 [4096][2048] (k-PERMUTED, SLOT-dense)
#define WS_AX    (WS_G + 4096*2048*2)      // bf16 [4096][1024]
#define WS_Y     WS_AX                     // y aliases Ax
#define WS_W1P   25296896ull               // bf16 W1 packed tiles, 64 MB
#define WS_W2P   (WS_W1P + 67108864ull)    // bf16 W2 packed tiles, 32 MB
#define WS_NEED  (WS_W2P + 33554432ull)    // ~126 MB

// Row k-permutation: pi(k) = ((k>>5)*4 + ((k>>2)&3))*8 + ((k>>4)&1)*4 + (k&3)

static __device__ __forceinline__ uint f2bf(float f) {
    uint u = __builtin_bit_cast(uint, f);
    return (u + 0x7FFFu + ((u >> 16) & 1u)) >> 16;   // RNE
}
static __device__ __forceinline__ float bflo(uint u) { return __builtin_bit_cast(float, u << 16); }
static __device__ __forceinline__ float bfhi(uint u) { return __builtin_bit_cast(float, u & 0xFFFF0000u); }
static __device__ __forceinline__ uint cvtpk(float a, float b) {
    uint r;
    asm("v_cvt_pk_bf16_f32 %0, %1, %2" : "=v"(r) : "v"(a), "v"(b));
    return r;
}
static __device__ __forceinline__ void gload_lds16(const void* g, void* l) {
    __builtin_amdgcn_global_load_lds(
        (const __attribute__((address_space(1))) unsigned int*)g,
        (__attribute__((address_space(3))) unsigned int*)l,
        16, 0, 0);
}
template<int N> static __device__ __forceinline__ void vmwait() {
    if constexpr (N == 0)      asm volatile("s_waitcnt vmcnt(0)" ::: "memory");
    else if constexpr (N == 1) asm volatile("s_waitcnt vmcnt(1)" ::: "memory");
    else if constexpr (N == 2) asm volatile("s_waitcnt vmcnt(2)" ::: "memory");
    else if constexpr (N == 3) asm volatile("s_waitcnt vmcnt(3)" ::: "memory");
    else if constexpr (N == 4) asm volatile("s_waitcnt vmcnt(4)" ::: "memory");
    else if constexpr (N == 6) asm volatile("s_waitcnt vmcnt(6)" ::: "memory");
}
static __device__ __forceinline__ void lgk0_bar() {
    asm volatile("s_waitcnt lgkmcnt(0)" ::: "memory");
    __builtin_amdgcn_sched_barrier(0);
    __builtin_amdgcn_s_barrier();
    asm volatile("" ::: "memory");
}
static __device__ __forceinline__ void raw_bar() {
    __builtin_amdgcn_sched_barrier(0);
    __builtin_amdgcn_s_barrier();
    asm volatile("" ::: "memory");
}

// ---------------- router ----------------
__global__ __launch_bounds__(256) void router_kernel(
    const float* __restrict__ x, const float* __restrict__ rw,
    int* __restrict__ cnt, int* __restrict__ list, float* __restrict__ w_entry)
{
    int wave = threadIdx.x >> 6, lane = threadIdx.x & 63;
    int n = blockIdx.x * 4 + wave;
    const float* xr = x + (size_t)n * H_DIM;
    float acc[8] = {0,0,0,0,0,0,0,0};
    #pragma unroll
    for (int i = 0; i < H_DIM/64; ++i) {
        int h = i*64 + lane;
        float xv = xr[h];
        const float4* rr = (const float4*)(rw + (size_t)h*8);
        float4 r0 = rr[0], r1 = rr[1];
        acc[0] += xv*r0.x; acc[1] += xv*r0.y; acc[2] += xv*r0.z; acc[3] += xv*r0.w;
        acc[4] += xv*r1.x; acc[5] += xv*r1.y; acc[6] += xv*r1.z; acc[7] += xv*r1.w;
    }
    #pragma unroll
    for (int e = 0; e < 8; ++e) {
        float v = acc[e];
        #pragma unroll
        for (int off = 32; off; off >>= 1) v += __shfl_xor(v, off);
        acc[e] = v;
    }
    int e0 = 0;
    #pragma unroll
    for (int e = 1; e < 8; ++e) if (acc[e] > acc[e0]) e0 = e;
    int e1 = -1;
    #pragma unroll
    for (int e = 0; e < 8; ++e) if (e != e0 && (e1 < 0 || acc[e] > acc[e1])) e1 = e;
    float w0 = 1.0f / (1.0f + __expf(acc[e1] - acc[e0]));
    float w1 = 1.0f - w0;
    if (lane == 0) {
        int p0 = atomicAdd(&cnt[e0], 1);
        list[e0*N_TOK + p0] = n*2;
        w_entry[n*2] = w0;
        int p1 = atomicAdd(&cnt[e1], 1);
        list[e1*N_TOK + p1] = n*2 + 1;
        w_entry[n*2+1] = w1;
    }
}

// ---------------- prefix ----------------
__global__ void prefix_kernel(const int* __restrict__ cnt, int* __restrict__ off) {
    if (threadIdx.x == 0) {
        int s = 0;
        #pragma unroll
        for (int e = 0; e < E_NUM; ++e) { off[e] = s; s += cnt[e]; }
        off[E_NUM] = s;
    }
}

// ---------------- gather ----------------
__global__ __launch_bounds__(256) void gather_kernel(
    const float* __restrict__ x, const int* __restrict__ cnt, const int* __restrict__ off,
    const int* __restrict__ list, unsigned short* __restrict__ Ax)
{
    int e = blockIdx.x >> 9;
    int r = (blockIdx.x & 511)*4 + (threadIdx.x >> 6);
    int lane = threadIdx.x & 63;
    if (r >= cnt[e]) return;
    int ent = list[e*N_TOK + r];
    const float* xr = x + (size_t)(ent >> 1) * H_DIM;
    unsigned short* dr = Ax + (size_t)(off[e] + r) * H_DIM;
    #pragma unroll
    for (int q = 0; q < 2; ++q) {
        int b = lane*2 + q;
        int t = b >> 3, s = b & 7;
        int klo = t*64 + (s >> 2)*32 + (s & 3)*4;
        float4 lo = *(const float4*)(xr + klo);
        float4 hi = *(const float4*)(xr + klo + 16);
        uint4 o;
        o.x = cvtpk(lo.x, lo.y); o.y = cvtpk(lo.z, lo.w);
        o.z = cvtpk(hi.x, hi.y); o.w = cvtpk(hi.z, hi.w);
        *(uint4*)(dr + b*8) = o;
    }
}

// ---------------- weight prepass: fp32 W -> bf16 swizzled Bs-image tiles ----------------
template<int IS_G1>
__global__ __launch_bounds__(256) void prep_w_kernel(
    const float* __restrict__ W, unsigned short* __restrict__ Wp)
{
    constexpr int NNT   = IS_G1 ? 32 : 16;
    constexpr int NSTEP = IS_G1 ? 32 : 64;
    constexpr int BLD   = IS_G1 ? 2*F_DIM : H_DIM;
    constexpr int BSROW = IS_G1 ? 512 : 256;
    constexpr int TILEB = 16 * BSROW;                 // 8 KB / 4 KB
    constexpr int NGR   = TILEB / 16;                 // granules (uint4)
    constexpr int C4N   = IS_G1 ? 32 : 16;

    int bid = blockIdx.x;
    int t  = bid % NSTEP;
    int nt = (bid / NSTEP) % NNT;
    int e  = bid / (NSTEP * NNT);
    const float* Wb = W + (size_t)e * (size_t)(IS_G1 ? H_DIM*2*F_DIM : F_DIM*H_DIM);
    char* tile = (char*)Wp + (size_t)bid * TILEB;

    #pragma unroll
    for (int s = 0; s < NGR/256; ++s) {
        int gidx = threadIdx.x + s*256;
        int kp = gidx / C4N, c4 = gidx % C4N;
        int k  = t*32 + 2*kp;
        int gc;
        if constexpr (IS_G1) gc = (c4 < 16) ? (nt*64 + 4*c4) : (F_DIM + nt*64 + 4*(c4-16));
        else                 gc = nt*64 + 4*c4;
        const float* p = Wb + (size_t)k * BLD + gc;
        float4 r0 = *(const float4*)p;
        float4 r1 = *(const float4*)(p + BLD);
        uint4 w4;
        w4.x = cvtpk(r0.x, r1.x); w4.y = cvtpk(r0.y, r1.y);
        w4.z = cvtpk(r0.z, r1.z); w4.w = cvtpk(r0.w, r1.w);
        *(uint4*)(tile + ((kp*BSROW + c4*16) ^ ((kp & 4) << 4))) = w4;
    }
}

// ---------------- pre-packed GEMM: pure-glds A and B, counted vmcnt ----------------
template<int IS_G1>
__global__ __launch_bounds__(256, IS_G1 ? 3 : 5) void moe_gemm_pre(
    const unsigned short* __restrict__ Asrc, const unsigned short* __restrict__ Wp,
    const int* __restrict__ cnt, const int* __restrict__ off,
    const int* __restrict__ list, const float* __restrict__ w_entry,
    unsigned short* __restrict__ dst)
{
    constexpr int KTOT  = IS_G1 ? H_DIM : F_DIM;
    constexpr int DLD   = IS_G1 ? F_DIM : H_DIM;
    constexpr int ALD   = IS_G1 ? H_DIM : F_DIM;
    constexpr int ROWS  = IS_G1 ? 128 : 64;
    constexpr int NM    = IS_G1 ? 8 : 2;
    constexpr int NA    = IS_G1 ? 4 : 2;
    constexpr int NMT   = IS_G1 ? 16 : 32;
    constexpr int NNT   = IS_G1 ? 32 : 16;
    constexpr int BSROW = IS_G1 ? 512 : 256;
    constexpr int TILEB = 16 * BSROW;                // bytes per 32k B tile
    constexpr int NBSG  = TILEB / 4096;              // B glds per wave per step (2 / 1)
    constexpr int NSTEP = KTOT / 32;
    constexpr int NP    = KTOT / 64;

    __shared__ __align__(16) unsigned short As[2][ROWS*64];
    __shared__ __align__(16) uint Bs[2][TILEB/4];

    constexpr int nb = NMT * NNT * E_NUM;
    constexpr int chunk = nb >> 3;
    int bid = blockIdx.x;
    int f  = (bid & 7) * chunk + (bid >> 3);
    int mt = f % NMT;
    int nt = (f / NMT) % NNT;
    int e  = f / (NMT * NNT);

    const int c = cnt[e];
    if (mt * ROWS >= c) return;
    const int abase = off[e] + mt * ROWS;
    const int tid = threadIdx.x;
    const int lane = tid & 63, wid = tid >> 6;
    const int l15 = lane & 15, lg = lane >> 4;
    const int wr = IS_G1 ? 0 : (wid >> 1);
    const int wc = wid & 1;
    const int rowbase = IS_G1 ? 0 : wr*32;

    // A staging sources (pre-swizzled; slot-dense rows)
    const unsigned short* a_src[NA];
    #pragma unroll
    for (int i = 0; i < NA; ++i) {
        int sl  = wid*(NA*1024) + i*1024 + lane*16;
        int row = sl >> 7;
        int kb  = ((sl >> 4) & 7) ^ (row & 7);
        int gr  = abase + row; gr = gr < 4095 ? gr : 4095;
        a_src[i] = Asrc + (size_t)gr * ALD + kb*8;
    }
    // B staging source: linear copy of pre-swizzled tile image.
    // PER-LANE global address (lane*16 bytes = 8 shorts) — R15's missing term.
    const unsigned short* bp = Wp + (size_t)((e*NNT + nt)*NSTEP) * (TILEB/2)
                             + wid*(TILEB/8) + lane*8;

    // fragment addresses (verified)
    int a_addr[NM][2];
    #pragma unroll
    for (int m = 0; m < NM; ++m)
        #pragma unroll
        for (int p = 0; p < 2; ++p) {
            int row = rowbase + m*16 + l15;
            a_addr[m][p] = row*128 + ((p*64 + lg*16) ^ ((row & 7) << 4));
        }
    int b_base[2];
    const int xorv = ((2*lg) & 4) << 4;
    #pragma unroll
    for (int j = 0; j < 2; ++j) {
        int cb = IS_G1 ? (j ? (4 + wid) : wid) : (wc*2 + j);
        b_base[j] = (2*lg)*BSROW + (((cb*16 + l15) * 4) ^ xorv);
    }

    f32x4 acc[NM][2];
    #pragma unroll
    for (int m = 0; m < NM; ++m)
        #pragma unroll
        for (int j = 0; j < 2; ++j) acc[m][j] = (f32x4){0.f,0.f,0.f,0.f};

    auto STAGE_A = [&](int p) {
        #pragma unroll
        for (int i = 0; i < NA; ++i)
            gload_lds16(a_src[i] + p*64, (char*)As[p & 1] + wid*(NA*1024) + i*1024);
    };
    auto STAGE_B = [&](int t) {
        #pragma unroll
        for (int i = 0; i < NBSG; ++i)
            gload_lds16(bp + (size_t)t*(TILEB/2) + i*512,
                        (char*)Bs[t & 1] + wid*(TILEB/4) + i*1024);
    };
    auto compute = [&](int P, int abuf) {
        const char* ab  = (const char*)As[abuf];
        const char* bb0 = (const char*)Bs[P];
        bf16x8 bfr[2];
        #pragma unroll
        for (int j = 0; j < 2; ++j) {
            const char* bb = bb0 + b_base[j];
            union { uint u[4]; bf16x8 v; } bu;
            bu.u[0] = *(const uint*)(bb);
            bu.u[1] = *(const uint*)(bb + BSROW);
            bu.u[2] = *(const uint*)(bb + 8*BSROW);
            bu.u[3] = *(const uint*)(bb + 9*BSROW);
            bfr[j] = bu.v;
        }
        #pragma unroll
        for (int m = 0; m < NM; ++m) {
            bf16x8 af = *(const bf16x8*)(ab + (P ? a_addr[m][1] : a_addr[m][0]));
            #pragma unroll
            for (int j = 0; j < 2; ++j)
                acc[m][j] = __builtin_amdgcn_mfma_f32_16x16x32_bf16(af, bfr[j], acc[m][j], 0, 0, 0);
        }
    };

    // ---- prologue: queue [A(0), B(0), B(1)] ----
    STAGE_A(0);
    STAGE_B(0);
    STAGE_B(1);

    // ---- main loop: 2 steps per pair; counted waits, never 0 ----
    for (int p = 0; p < NP - 1; ++p) {
        vmwait<NBSG>();                  // A(p), B(2p) landed; B(2p+1) in flight
        raw_bar();
        compute(0, p & 1);               // reads As[p&1] half0, Bs[0]
        raw_bar();                       // Bs[0] readers done
        STAGE_B(2*p + 2);                // -> Bs[0]
        STAGE_A(p + 1);                  // -> As[(p+1)&1]
        vmwait<NBSG + NA>();             // B(2p+1) landed; B(2p+2), A(p+1) in flight
        raw_bar();
        compute(1, p & 1);               // reads As[p&1] half1, Bs[1]
        raw_bar();                       // Bs[1] readers done
        STAGE_B(2*p + 3);                // -> Bs[1]
    }
    // ---- tail pair ----
    {
        const int ab = (NP - 1) & 1;
        vmwait<NBSG>();
        raw_bar();
        compute(0, ab);
        vmwait<0>();
        raw_bar();
        compute(1, ab);
    }

    // ---- epilogue (verified forms) ----
    if constexpr (IS_G1) {
        const int pbase = nt*64 + ((wid >> 1)*4 + (l15 >> 2))*8 + (wid & 1)*4 + (l15 & 3);
        #pragma unroll
        for (int m = 0; m < NM; ++m) {
            f32x4 ga = acc[m][0], gv = acc[m][1];
            #pragma unroll
            for (int i = 0; i < 4; ++i) {
                int rl = m*16 + lg*4 + i;
                if (mt*ROWS + rl < c) {
                    float a = ga[i];
                    float g = (a / (1.f + __expf(-a))) * gv[i];
                    dst[(size_t)(abase + rl) * DLD + pbase] = (unsigned short)f2bf(g);
                }
            }
        }
    } else {
        const int lbase = e * N_TOK + mt * ROWS;
        #pragma unroll
        for (int m = 0; m < NM; ++m)
            #pragma unroll
            for (int i = 0; i < 4; ++i) {
                int rl = rowbase + m*16 + lg*4 + i;
                if (mt*ROWS + rl < c) {
                    int ent = list[lbase + rl];
                    float w = w_entry[ent];
                    #pragma unroll
                    for (int j = 0; j < 2; ++j) {
                        int col = nt*64 + wc*32 + j*16 + l15;
                        dst[(size_t)ent * DLD + col] = (unsigned short)f2bf(w * acc[m][j][i]);
                    }
                }
            }
    }
}

// ---------------- fallback fp32-B GEMM (R14 verbatim) ----------------
template<int IS_G1>
__global__ __launch_bounds__(256, IS_G1 ? 3 : 5) void moe_gemm_kernel(
    const unsigned short* __restrict__ Asrc, const float* __restrict__ W,
    const int* __restrict__ cnt, const int* __restrict__ off,
    const int* __restrict__ list, const float* __restrict__ w_entry,
    unsigned short* __restrict__ dst)
{
    constexpr int KTOT  = IS_G1 ? H_DIM : F_DIM;
    constexpr int BLD   = IS_G1 ? 2*F_DIM : H_DIM;
    constexpr int DLD   = IS_G1 ? F_DIM : H_DIM;
    constexpr int ALD   = IS_G1 ? H_DIM : F_DIM;
    constexpr int ROWS  = IS_G1 ? 128 : 64;
    constexpr int NM    = IS_G1 ? 8 : 2;
    constexpr int NA    = IS_G1 ? 4 : 2;
    constexpr int NMT   = IS_G1 ? 16 : 32;
    constexpr int NNT   = IS_G1 ? 32 : 16;
    constexpr int BSROW = IS_G1 ? 512 : 256;
    constexpr int NBS   = IS_G1 ? 2 : 1;
    constexpr int NT2   = KTOT / 64;

    __shared__ __align__(16) unsigned short As[2][ROWS*64];
    __shared__ __align__(16) uint Bs[2][16*BSROW/4];

    constexpr int nb = NMT * NNT * E_NUM;
    constexpr int chunk = nb >> 3;
    int bid = blockIdx.x;
    int f  = (bid & 7) * chunk + (bid >> 3);
    int mt = f % NMT;
    int nt = (f / NMT) % NNT;
    int e  = f / (NMT * NNT);

    const int c = cnt[e];
    if (mt * ROWS >= c) return;
    const int abase = off[e] + mt * ROWS;
    const int tid = threadIdx.x;
    const int lane = tid & 63, wid = tid >> 6;
    const int l15 = lane & 15, lg = lane >> 4;
    const int wr = IS_G1 ? 0 : (wid >> 1);
    const int wc = wid & 1;
    const int rowbase = IS_G1 ? 0 : wr*32;

    const unsigned short* a_src[NA];
    #pragma unroll
    for (int i = 0; i < NA; ++i) {
        int sl  = wid*(NA*1024) + i*1024 + lane*16;
        int row = sl >> 7;
        int kb  = ((sl >> 4) & 7) ^ (row & 7);
        int gr  = abase + row; gr = gr < 4095 ? gr : 4095;
        a_src[i] = Asrc + (size_t)gr * ALD + kb*8;
    }

    const float* Wb = W + (size_t)e * (size_t)(IS_G1 ? H_DIM*2*F_DIM : F_DIM*H_DIM);
    const float* b_src[NBS]; int b_dst[NBS];
    #pragma unroll
    for (int s = 0; s < NBS; ++s) {
        int q = tid + s*256;
        int kp, c4, gc;
        if constexpr (IS_G1) {
            kp = q >> 5; c4 = q & 31;
            gc = (c4 < 16) ? (nt*64 + 4*c4) : (F_DIM + nt*64 + 4*(c4-16));
        } else {
            kp = q >> 4; c4 = q & 15;
            gc = nt*64 + 4*c4;
        }
        b_src[s] = Wb + (size_t)(2*kp) * BLD + gc;
        b_dst[s] = (kp*BSROW + c4*16) ^ ((kp & 4) << 4);
    }

    int a_addr[NM][2];
    #pragma unroll
    for (int m = 0; m < NM; ++m)
        #pragma unroll
        for (int p = 0; p < 2; ++p) {
            int row = rowbase + m*16 + l15;
            a_addr[m][p] = row*128 + ((p*64 + lg*16) ^ ((row & 7) << 4));
        }
    int b_base[2];
    const int xorv = ((2*lg) & 4) << 4;
    #pragma unroll
    for (int j = 0; j < 2; ++j) {
        int cb = IS_G1 ? (j ? (4 + wid) : wid) : (wc*2 + j);
        b_base[j] = (2*lg)*BSROW + (((cb*16 + l15) * 4) ^ xorv);
    }

    f32x4 acc[NM][2];
    #pragma unroll
    for (int m = 0; m < NM; ++m)
        #pragma unroll
        for (int j = 0; j < 2; ++j) acc[m][j] = (f32x4){0.f,0.f,0.f,0.f};

    struct BQ { float4 r0[NBS], r1[NBS]; };
    auto loadB = [&](int t) {
        BQ q;
        #pragma unroll
        for (int s = 0; s < NBS; ++s) {
            const float* p = b_src[s] + (size_t)t * 32 * BLD;
            q.r0[s] = *(const float4*)p;
            q.r1[s] = *(const float4*)(p + BLD);
        }
        return q;
    };
    auto dswB = [&](const BQ& q, int buf) {
        #pragma unroll
        for (int s = 0; s < NBS; ++s) {
            uint4 w4;
            w4.x = cvtpk(q.r0[s].x, q.r1[s].x); w4.y = cvtpk(q.r0[s].y, q.r1[s].y);
            w4.z = cvtpk(q.r0[s].z, q.r1[s].z); w4.w = cvtpk(q.r0[s].w, q.r1[s].w);
            *(uint4*)((char*)Bs[buf] + b_dst[s]) = w4;
        }
    };
    auto STAGE_A = [&](int a) {
        #pragma unroll
        for (int i = 0; i < NA; ++i)
            gload_lds16(a_src[i] + a*64, (char*)As[a & 1] + wid*(NA*1024) + i*1024);
    };
    auto compute = [&](int P, int abuf) {
        const char* ab  = (const char*)As[abuf];
        const char* bb0 = (const char*)Bs[P];
        bf16x8 bfr[2];
        #pragma unroll
        for (int j = 0; j < 2; ++j) {
            const char* bb = bb0 + b_base[j];
            union { uint u[4]; bf16x8 v; } bu;
            bu.u[0] = *(const uint*)(bb);
            bu.u[1] = *(const uint*)(bb + BSROW);
            bu.u[2] = *(const uint*)(bb + 8*BSROW);
            bu.u[3] = *(const uint*)(bb + 9*BSROW);
            bfr[j] = bu.v;
        }
        #pragma unroll
        for (int m = 0; m < NM; ++m) {
            bf16x8 af = *(const bf16x8*)(ab + (P ? a_addr[m][1] : a_addr[m][0]));
            #pragma unroll
            for (int j = 0; j < 2; ++j)
                acc[m][j] = __builtin_amdgcn_mfma_f32_16x16x32_bf16(af, bfr[j], acc[m][j], 0, 0, 0);
        }
    };

    STAGE_A(0);
    { BQ q0 = loadB(0); dswB(q0, 0); }
    BQ qW = loadB(1);
    BQ qN;

    for (int tp = 0; tp < NT2 - 1; ++tp) {
        vmwait<2*NBS>(); __builtin_amdgcn_sched_barrier(0);
        lgk0_bar();
        STAGE_A(tp + 1);
        qN = loadB(2*tp + 2);
        compute(0, tp & 1);
        dswB(qW, 1);
        lgk0_bar();
        qW = loadB(2*tp + 3);
        compute(1, tp & 1);
        dswB(qN, 0);
    }
    {
        const int ab = (NT2 - 1) & 1;
        vmwait<2*NBS>(); __builtin_amdgcn_sched_barrier(0);
        lgk0_bar();
        compute(0, ab);
        dswB(qW, 1);
        lgk0_bar();
        compute(1, ab);
    }

    if constexpr (IS_G1) {
        const int pbase = nt*64 + ((wid >> 1)*4 + (l15 >> 2))*8 + (wid & 1)*4 + (l15 & 3);
        #pragma unroll
        for (int m = 0; m < NM; ++m) {
            f32x4 ga = acc[m][0], gv = acc[m][1];
            #pragma unroll
            for (int i = 0; i < 4; ++i) {
                int rl = m*16 + lg*4 + i;
                if (mt*ROWS + rl < c) {
                    float a = ga[i];
                    float g = (a / (1.f + __expf(-a))) * gv[i];
                    dst[(size_t)(abase + rl) * DLD + pbase] = (unsigned short)f2bf(g);
                }
            }
        }
    } else {
        const int lbase = e * N_TOK + mt * ROWS;
        #pragma unroll
        for (int m = 0; m < NM; ++m)
            #pragma unroll
            for (int i = 0; i < 4; ++i) {
                int rl = rowbase + m*16 + lg*4 + i;
                if (mt*ROWS + rl < c) {
                    int ent = list[lbase + rl];
                    float w = w_entry[ent];
                    #pragma unroll
                    for (int j = 0; j < 2; ++j) {
                        int col = nt*64 + wc*32 + j*16 + l15;
                        dst[(size_t)ent * DLD + col] = (unsigned short)f2bf(w * acc[m][j][i]);
                    }
                }
            }
    }
}

// ---------------- combine ----------------
__global__ __launch_bounds__(256) void combine_kernel(
    const unsigned short* __restrict__ y, float* __restrict__ out)
{
    int gid = blockIdx.x * 256 + threadIdx.x;
    size_t base = (size_t)gid * 8;
    int n = (int)(base >> 10), h = (int)(base & 1023);
    const uint4 a = *(const uint4*)(y + (size_t)(2*n)   * 1024 + h);
    const uint4 b = *(const uint4*)(y + (size_t)(2*n+1) * 1024 + h);
    float4 o0, o1;
    o0.x = bflo(a.x)+bflo(b.x); o0.y = bfhi(a.x)+bfhi(b.x);
    o0.z = bflo(a.y)+bflo(b.y); o0.w = bfhi(a.y)+bfhi(b.y);
    o1.x = bflo(a.z)+bflo(b.z); o1.y = bfhi(a.z)+bfhi(b.z);
    o1.z = bflo(a.w)+bflo(b.w); o1.w = bfhi(a.w)+bfhi(b.w);
    *(float4*)(out + base)     = o0;
    *(float4*)(out + base + 4) = o1;
}

extern "C" void kernel_launch(void* const* d_in, const int* in_sizes, int n_in,
                              void* d_out, int out_size, void* d_ws, size_t ws_size,
                              hipStream_t stream) {
    const float* x  = (const float*)d_in[0];
    const float* rw = (const float*)d_in[1];
    const float* W1 = (const float*)d_in[2];
    const float* W2 = (const float*)d_in[3];
    float* out = (float*)d_out;
    char* ws = (char*)d_ws;
    int*   cnt     = (int*)(ws + WS_CNT);
    int*   off     = (int*)(ws + WS_OFF);
    int*   list    = (int*)(ws + WS_LIST);
    float* w_entry = (float*)(ws + WS_W);
    unsigned short* g  = (unsigned short*)(ws + WS_G);
    unsigned short* Ax = (unsigned short*)(ws + WS_AX);
    unsigned short* y  = (unsigned short*)(ws + WS_Y);

    hipMemsetAsync(cnt, 0, E_NUM * sizeof(int), stream);
    router_kernel<<<N_TOK/4, 256, 0, stream>>>(x, rw, cnt, list, w_entry);
    prefix_kernel<<<1, 64, 0, stream>>>(cnt, off);
    gather_kernel<<<E_NUM*512, 256, 0, stream>>>(x, cnt, off, list, Ax);

    if (ws_size >= WS_NEED) {
        unsigned short* W1p = (unsigned short*)(ws + WS_W1P);
        unsigned short* W2p = (unsigned short*)(ws + WS_W2P);
        prep_w_kernel<1><<<E_NUM*32*32, 256, 0, stream>>>(W1, W1p);
        prep_w_kernel<0><<<E_NUM*16*64, 256, 0, stream>>>(W2, W2p);
        moe_gemm_pre<1><<<16*32*E_NUM, 256, 0, stream>>>(Ax, W1p, cnt, off, list, w_entry, g);
        moe_gemm_pre<0><<<32*16*E_NUM, 256, 0, stream>>>(g,  W2p, cnt, off, list, w_entry, y);
    } else {
        moe_gemm_kernel<1><<<16*32*E_NUM, 256, 0, stream>>>(Ax, W1, cnt, off, list, w_entry, g);
        moe_gemm_kernel<0><<<32*16*E_NUM, 256, 0, stream>>>(g,  W2, cnt, off, list, w_entry, y);
    }
    combine_kernel<<<(out_size/8 + 255)/256, 256, 0, stream>>>(y, out);
}

// Round 17
// 203.724 us; speedup vs baseline: 1.1878x; 1.1878x over previous
//
#include <hip/hip_runtime.h>
#include <hip/hip_bf16.h>

#define H_DIM 1024
#define E_NUM 8
#define F_DIM 2048
#define N_TOK 2048   // B*S
typedef unsigned int uint;
typedef short bf16x8 __attribute__((ext_vector_type(8)));
typedef float f32x4 __attribute__((ext_vector_type(4)));

// ws layout (24.25 MB)
#define WS_CNT   0
#define WS_OFF   64                        // int[9] exclusive prefix of cnt
#define WS_LIST  256                       // int[8*2048]
#define WS_W     (WS_LIST + 8*N_TOK*4)     // float[4096]
#define WS_G     131072                    // bf16 [4096][2048] (k-PERMUTED, SLOT-dense)
#define WS_AX    (WS_G + 4096*2048*2)      // bf16 [4096][1024] (k-PERMUTED, SLOT-dense)
#define WS_Y     WS_AX                     // y aliases Ax (Ax dead after G1)

// Row k-permutation: storage position of element k is
//   pi(k) = ((k>>5)*4 + ((k>>2)&3))*8 + ((k>>4)&1)*4 + (k&3)  (per 64-k block)

static __device__ __forceinline__ uint f2bf(float f) {
    uint u = __builtin_bit_cast(uint, f);
    return (u + 0x7FFFu + ((u >> 16) & 1u)) >> 16;   // RNE
}
static __device__ __forceinline__ float bflo(uint u) { return __builtin_bit_cast(float, u << 16); }
static __device__ __forceinline__ float bfhi(uint u) { return __builtin_bit_cast(float, u & 0xFFFF0000u); }
static __device__ __forceinline__ uint cvtpk(float a, float b) {
    uint r;
    asm("v_cvt_pk_bf16_f32 %0, %1, %2" : "=v"(r) : "v"(a), "v"(b));
    return r;
}
static __device__ __forceinline__ void gload_lds16(const void* g, void* l) {
    __builtin_amdgcn_global_load_lds(
        (const __attribute__((address_space(1))) unsigned int*)g,
        (__attribute__((address_space(3))) unsigned int*)l,
        16, 0, 0);
}
template<int N> static __device__ __forceinline__ void vmwait() {
    if constexpr (N == 0)      asm volatile("s_waitcnt vmcnt(0)" ::: "memory");
    else if constexpr (N == 2) asm volatile("s_waitcnt vmcnt(2)" ::: "memory");
    else if constexpr (N == 4) asm volatile("s_waitcnt vmcnt(4)" ::: "memory");
}
// lgkmcnt(0) + sched fence + barrier + fence: makes own ds_writes visible and
// separates all preceding LDS reads from subsequent writes (double-buffer handoff).
static __device__ __forceinline__ void lgk0_bar() {
    asm volatile("s_waitcnt lgkmcnt(0)" ::: "memory");
    __builtin_amdgcn_sched_barrier(0);
    __builtin_amdgcn_s_barrier();
    asm volatile("" ::: "memory");
}

// ---------------- router ----------------
__global__ __launch_bounds__(256) void router_kernel(
    const float* __restrict__ x, const float* __restrict__ rw,
    int* __restrict__ cnt, int* __restrict__ list, float* __restrict__ w_entry)
{
    int wave = threadIdx.x >> 6, lane = threadIdx.x & 63;
    int n = blockIdx.x * 4 + wave;
    const float* xr = x + (size_t)n * H_DIM;
    float acc[8] = {0,0,0,0,0,0,0,0};
    #pragma unroll
    for (int i = 0; i < H_DIM/64; ++i) {
        int h = i*64 + lane;
        float xv = xr[h];
        const float4* rr = (const float4*)(rw + (size_t)h*8);
        float4 r0 = rr[0], r1 = rr[1];
        acc[0] += xv*r0.x; acc[1] += xv*r0.y; acc[2] += xv*r0.z; acc[3] += xv*r0.w;
        acc[4] += xv*r1.x; acc[5] += xv*r1.y; acc[6] += xv*r1.z; acc[7] += xv*r1.w;
    }
    #pragma unroll
    for (int e = 0; e < 8; ++e) {
        float v = acc[e];
        #pragma unroll
        for (int off = 32; off; off >>= 1) v += __shfl_xor(v, off);
        acc[e] = v;
    }
    int e0 = 0;
    #pragma unroll
    for (int e = 1; e < 8; ++e) if (acc[e] > acc[e0]) e0 = e;
    int e1 = -1;
    #pragma unroll
    for (int e = 0; e < 8; ++e) if (e != e0 && (e1 < 0 || acc[e] > acc[e1])) e1 = e;
    float w0 = 1.0f / (1.0f + __expf(acc[e1] - acc[e0]));
    float w1 = 1.0f - w0;
    if (lane == 0) {
        int p0 = atomicAdd(&cnt[e0], 1);
        list[e0*N_TOK + p0] = n*2;
        w_entry[n*2] = w0;
        int p1 = atomicAdd(&cnt[e1], 1);
        list[e1*N_TOK + p1] = n*2 + 1;
        w_entry[n*2+1] = w1;
    }
}

// ---------------- prefix ----------------
__global__ void prefix_kernel(const int* __restrict__ cnt, int* __restrict__ off) {
    if (threadIdx.x == 0) {
        int s = 0;
        #pragma unroll
        for (int e = 0; e < E_NUM; ++e) { off[e] = s; s += cnt[e]; }
        off[E_NUM] = s;
    }
}

// ---------------- gather: x[token] -> Ax[slot] bf16 k-permuted ----------------
__global__ __launch_bounds__(256) void gather_kernel(
    const float* __restrict__ x, const int* __restrict__ cnt, const int* __restrict__ off,
    const int* __restrict__ list, unsigned short* __restrict__ Ax)
{
    int e = blockIdx.x >> 9;
    int r = (blockIdx.x & 511)*4 + (threadIdx.x >> 6);
    int lane = threadIdx.x & 63;
    if (r >= cnt[e]) return;
    int ent = list[e*N_TOK + r];
    const float* xr = x + (size_t)(ent >> 1) * H_DIM;
    unsigned short* dr = Ax + (size_t)(off[e] + r) * H_DIM;
    #pragma unroll
    for (int q = 0; q < 2; ++q) {
        int b = lane*2 + q;
        int t = b >> 3, s = b & 7;
        int klo = t*64 + (s >> 2)*32 + (s & 3)*4;
        float4 lo = *(const float4*)(xr + klo);
        float4 hi = *(const float4*)(xr + klo + 16);
        uint4 o;
        o.x = cvtpk(lo.x, lo.y); o.y = cvtpk(lo.z, lo.w);
        o.z = cvtpk(hi.x, hi.y); o.w = cvtpk(hi.z, hi.w);
        *(uint4*)(dr + b*8) = o;
    }
}

// ---------------- fused expert GEMM ----------------
// R6 geometry + counted-vmcnt schedule, DOUBLE-BUFFERED Bs (race-free handoff:
// every Bs write is separated from that buffer's readers by a lgk0_bar).
// compute(0) reads Bs[0] (even 32k step), compute(1) reads Bs[1] (odd step).
template<int IS_G1>
__global__ __launch_bounds__(256, IS_G1 ? 4 : 5) void moe_gemm_kernel(
    const unsigned short* __restrict__ Asrc, const float* __restrict__ W,
    const int* __restrict__ cnt, const int* __restrict__ off,
    const int* __restrict__ list, const float* __restrict__ w_entry,
    unsigned short* __restrict__ dst)
{
    constexpr int KTOT  = IS_G1 ? H_DIM : F_DIM;
    constexpr int BLD   = IS_G1 ? 2*F_DIM : H_DIM;   // W row stride (fp32)
    constexpr int DLD   = IS_G1 ? F_DIM : H_DIM;     // dst row stride
    constexpr int ALD   = IS_G1 ? H_DIM : F_DIM;     // A src row stride (shorts)
    constexpr int ROWS  = 64;
    constexpr int NM    = IS_G1 ? 4 : 2;
    constexpr int NMT   = 32;
    constexpr int NNT   = IS_G1 ? 32 : 16;
    constexpr int BSROW = IS_G1 ? 512 : 256;         // Bs kpair row bytes
    constexpr int NBS   = IS_G1 ? 2 : 1;             // uint4 Bs slots per thread
    constexpr int NT2   = KTOT / 64;                 // 64k pairs

    __shared__ __align__(16) unsigned short As[2][ROWS*64];  // 2 x 8 KB
    __shared__ __align__(16) uint Bs[2][16*BSROW/4];         // 2 x 8/4 KB bf16 kpair

    constexpr int nb = NMT * NNT * E_NUM;
    constexpr int chunk = nb >> 3;
    int bid = blockIdx.x;
    int f  = (bid & 7) * chunk + (bid >> 3);
    int mt = f % NMT;
    int nt = (f / NMT) % NNT;
    int e  = f / (NMT * NNT);

    const int c = cnt[e];
    if (mt * ROWS >= c) return;
    const int abase = off[e] + mt * ROWS;
    const int tid = threadIdx.x;
    const int lane = tid & 63, wid = tid >> 6;
    const int l15 = lane & 15, lg = lane >> 4;
    const int wr = IS_G1 ? 0 : (wid >> 1);
    const int wc = wid & 1;
    const int rowbase = IS_G1 ? 0 : wr*32;

    // A staging sources (pre-swizzled: linear glds dest == bank-swizzled layout)
    const unsigned short* a_src[2];
    #pragma unroll
    for (int i = 0; i < 2; ++i) {
        int sl  = wid*2048 + i*1024 + lane*16;
        int row = sl >> 7;
        int kb  = ((sl >> 4) & 7) ^ (row & 7);
        int gr  = abase + row; gr = gr < 4095 ? gr : 4095;
        a_src[i] = Asrc + (size_t)gr * ALD + kb*8;
    }

    // B staging (verified BK=32 forms)
    const float* Wb = W + (size_t)e * (size_t)(IS_G1 ? H_DIM*2*F_DIM : F_DIM*H_DIM);
    const float* b_src[NBS]; int b_dst[NBS];
    #pragma unroll
    for (int s = 0; s < NBS; ++s) {
        int q = tid + s*256;
        int kp, c4, gc;
        if constexpr (IS_G1) {
            kp = q >> 5; c4 = q & 31;
            gc = (c4 < 16) ? (nt*64 + 4*c4) : (F_DIM + nt*64 + 4*(c4-16));
        } else {
            kp = q >> 4; c4 = q & 15;
            gc = nt*64 + 4*c4;
        }
        b_src[s] = Wb + (size_t)(2*kp) * BLD + gc;
        b_dst[s] = (kp*BSROW + c4*16) ^ ((kp & 4) << 4);
    }

    // fragment addresses (verified)
    int a_addr[NM][2];
    #pragma unroll
    for (int m = 0; m < NM; ++m)
        #pragma unroll
        for (int p = 0; p < 2; ++p) {
            int row = rowbase + m*16 + l15;
            a_addr[m][p] = row*128 + ((p*64 + lg*16) ^ ((row & 7) << 4));
        }
    int b_base[2];
    const int xorv = ((2*lg) & 4) << 4;
    #pragma unroll
    for (int j = 0; j < 2; ++j) {
        int cb = IS_G1 ? (j ? (4 + wid) : wid) : (wc*2 + j);
        b_base[j] = (2*lg)*BSROW + (((cb*16 + l15) * 4) ^ xorv);
    }

    f32x4 acc[NM][2];
    #pragma unroll
    for (int m = 0; m < NM; ++m)
        #pragma unroll
        for (int j = 0; j < 2; ++j) acc[m][j] = (f32x4){0.f,0.f,0.f,0.f};

    struct BQ { float4 r0[NBS], r1[NBS]; };
    auto loadB = [&](int t) {
        BQ q;
        #pragma unroll
        for (int s = 0; s < NBS; ++s) {
            const float* p = b_src[s] + (size_t)t * 32 * BLD;
            q.r0[s] = *(const float4*)p;
            q.r1[s] = *(const float4*)(p + BLD);
        }
        return q;
    };
    auto dswB = [&](const BQ& q, int buf) {
        #pragma unroll
        for (int s = 0; s < NBS; ++s) {
            uint4 w4;
            w4.x = cvtpk(q.r0[s].x, q.r1[s].x); w4.y = cvtpk(q.r0[s].y, q.r1[s].y);
            w4.z = cvtpk(q.r0[s].z, q.r1[s].z); w4.w = cvtpk(q.r0[s].w, q.r1[s].w);
            *(uint4*)((char*)Bs[buf] + b_dst[s]) = w4;
        }
    };
    auto STAGE_A = [&](int a) {
        #pragma unroll
        for (int i = 0; i < 2; ++i)
            gload_lds16(a_src[i] + a*64, (char*)As[a & 1] + wid*2048 + i*1024);
    };
    auto compute = [&](int P, int abuf) {            // P literal at call sites; B buffer == P
        const char* ab  = (const char*)As[abuf];
        const char* bb0 = (const char*)Bs[P];
        bf16x8 bfr[2];
        #pragma unroll
        for (int j = 0; j < 2; ++j) {
            const char* bb = bb0 + b_base[j];
            union { uint u[4]; bf16x8 v; } bu;
            bu.u[0] = *(const uint*)(bb);
            bu.u[1] = *(const uint*)(bb + BSROW);
            bu.u[2] = *(const uint*)(bb + 8*BSROW);
            bu.u[3] = *(const uint*)(bb + 9*BSROW);
            bfr[j] = bu.v;
        }
        #pragma unroll
        for (int m = 0; m < NM; ++m) {
            bf16x8 af = *(const bf16x8*)(ab + (P ? a_addr[m][1] : a_addr[m][0]));
            #pragma unroll
            for (int j = 0; j < 2; ++j)
                acc[m][j] = __builtin_amdgcn_mfma_f32_16x16x32_bf16(af, bfr[j], acc[m][j], 0, 0, 0);
        }
    };

    // ---- prologue ----
    STAGE_A(0);
    { BQ q0 = loadB(0); dswB(q0, 0); }   // compiler drains (one-time); Bs[0] = B(0)
    BQ qW = loadB(1);
    BQ qN;

    // ---- main loop: one lgk0_bar per 32k step; writes always target the buffer
    //      whose readers finished before the previous barrier ----
    for (int tp = 0; tp < NT2 - 1; ++tp) {
        vmwait<2*NBS>(); __builtin_amdgcn_sched_barrier(0);
        lgk0_bar();                      // Bs[0]=B(2tp) visible; A(tp) ready (drained prev pair)
        STAGE_A(tp + 1);
        qN = loadB(2*tp + 2);
        compute(0, tp & 1);              // reads Bs[0]
        dswB(qW, 1);                     // write B(2tp+1) -> Bs[1] (readers done: prev entry bar)
        lgk0_bar();                      // Bs[1] visible; Bs[0] readers done
        qW = loadB(2*tp + 3);
        compute(1, tp & 1);              // reads Bs[1]
        dswB(qN, 0);                     // write B(2tp+2) -> Bs[0] (readers done: mid bar)
    }
    // ---- tail pair tp = NT2-1 ----
    {
        const int ab = (NT2 - 1) & 1;
        vmwait<2*NBS>(); __builtin_amdgcn_sched_barrier(0);
        lgk0_bar();
        compute(0, ab);
        dswB(qW, 1);                     // compiler waits qW loads
        lgk0_bar();
        compute(1, ab);
    }

    // ---- epilogue ----
    if constexpr (IS_G1) {
        const int pbase = nt*64 + ((wid >> 1)*4 + (l15 >> 2))*8 + (wid & 1)*4 + (l15 & 3);
        #pragma unroll
        for (int m = 0; m < NM; ++m) {
            f32x4 ga = acc[m][0], gv = acc[m][1];
            #pragma unroll
            for (int i = 0; i < 4; ++i) {
                int rl = m*16 + lg*4 + i;
                if (mt*ROWS + rl < c) {
                    float a = ga[i];
                    float g = (a / (1.f + __expf(-a))) * gv[i];
                    dst[(size_t)(abase + rl) * DLD + pbase] = (unsigned short)f2bf(g);
                }
            }
        }
    } else {
        const int lbase = e * N_TOK + mt * ROWS;
        #pragma unroll
        for (int m = 0; m < NM; ++m)
            #pragma unroll
            for (int i = 0; i < 4; ++i) {
                int rl = rowbase + m*16 + lg*4 + i;
                if (mt*ROWS + rl < c) {
                    int ent = list[lbase + rl];
                    float w = w_entry[ent];
                    #pragma unroll
                    for (int j = 0; j < 2; ++j) {
                        int col = nt*64 + wc*32 + j*16 + l15;
                        dst[(size_t)ent * DLD + col] = (unsigned short)f2bf(w * acc[m][j][i]);
                    }
                }
            }
    }
}

// ---------------- combine ----------------
__global__ __launch_bounds__(256) void combine_kernel(
    const unsigned short* __restrict__ y, float* __restrict__ out)
{
    int gid = blockIdx.x * 256 + threadIdx.x;
    size_t base = (size_t)gid * 8;
    int n = (int)(base >> 10), h = (int)(base & 1023);
    const uint4 a = *(const uint4*)(y + (size_t)(2*n)   * 1024 + h);
    const uint4 b = *(const uint4*)(y + (size_t)(2*n+1) * 1024 + h);
    float4 o0, o1;
    o0.x = bflo(a.x)+bflo(b.x); o0.y = bfhi(a.x)+bfhi(b.x);
    o0.z = bflo(a.y)+bflo(b.y); o0.w = bfhi(a.y)+bfhi(b.y);
    o1.x = bflo(a.z)+bflo(b.z); o1.y = bfhi(a.z)+bfhi(b.z);
    o1.z = bflo(a.w)+bflo(b.w); o1.w = bfhi(a.w)+bfhi(b.w);
    *(float4*)(out + base)     = o0;
    *(float4*)(out + base + 4) = o1;
}

extern "C" void kernel_launch(void* const* d_in, const int* in_sizes, int n_in,
                              void* d_out, int out_size, void* d_ws, size_t ws_size,
                              hipStream_t stream) {
    const float* x  = (const float*)d_in[0];
    const float* rw = (const float*)d_in[1];
    const float* W1 = (const float*)d_in[2];
    const float* W2 = (const float*)d_in[3];
    float* out = (float*)d_out;
    char* ws = (char*)d_ws;
    int*   cnt     = (int*)(ws + WS_CNT);
    int*   off     = (int*)(ws + WS_OFF);
    int*   list    = (int*)(ws + WS_LIST);
    float* w_entry = (float*)(ws + WS_W);
    unsigned short* g  = (unsigned short*)(ws + WS_G);
    unsigned short* Ax = (unsigned short*)(ws + WS_AX);
    unsigned short* y  = (unsigned short*)(ws + WS_Y);

    hipMemsetAsync(cnt, 0, E_NUM * sizeof(int), stream);
    router_kernel<<<N_TOK/4, 256, 0, stream>>>(x, rw, cnt, list, w_entry);
    prefix_kernel<<<1, 64, 0, stream>>>(cnt, off);
    gather_kernel<<<E_NUM*512, 256, 0, stream>>>(x, cnt, off, list, Ax);
    moe_gemm_kernel<1><<<32*32*E_NUM, 256, 0, stream>>>(Ax, W1, cnt, off, list, w_entry, g);
    moe_gemm_kernel<0><<<32*16*E_NUM, 256, 0, stream>>>(g,  W2, cnt, off, list, w_entry, y);
    combine_kernel<<<(out_size/8 + 255)/256, 256, 0, stream>>>(y, out);
}